// Round 8
// baseline (50532.852 us; speedup 1.0000x reference)
//
#include <hip/hip_runtime.h>

typedef unsigned short u16;
typedef unsigned int u32;
typedef unsigned long long u64;
typedef __attribute__((ext_vector_type(8))) short bf16x8;   // 8 bf16 = 4 VGPRs
typedef __attribute__((ext_vector_type(4))) float f32x4;

namespace {
constexpr int kT = 1024, kI = 64, kH = 512, kO = 24;
constexpr int kB = 64;
constexpr int kBH = kB * kH;                  // 32768 elems per h buffer (bf16)
constexpr unsigned kBarOff = 8u * (unsigned)kBH * 2u;  // 4 h1 + 4 h2 bufs = 524288 B
}

__device__ __forceinline__ u16 f2bf(float f) {   // round-to-nearest-even
  union { float f; u32 u; } c; c.f = f;
  u32 u = c.u + 0x7FFFu + ((c.u >> 16) & 1u);
  return (u16)(u >> 16);
}
__device__ __forceinline__ float sigf(float x) { return 1.0f / (1.0f + __expf(-x)); }
__device__ __forceinline__ float tanhf_(float x) {
  float e = __expf(2.0f * x); return 1.0f - 2.0f / (e + 1.0f);  // safe at +-inf
}
__device__ __forceinline__ bf16x8 cvt8(const float* p) {  // fp32x8 -> bf16x8 (RNE)
  const float4 f0 = *reinterpret_cast<const float4*>(p);
  const float4 f1 = *reinterpret_cast<const float4*>(p + 4);
  bf16x8 r;
  r[0] = (short)f2bf(f0.x); r[1] = (short)f2bf(f0.y);
  r[2] = (short)f2bf(f0.z); r[3] = (short)f2bf(f0.w);
  r[4] = (short)f2bf(f1.x); r[5] = (short)f2bf(f1.y);
  r[6] = (short)f2bf(f1.z); r[7] = (short)f2bf(f1.w);
  return r;
}
// agent-coherent 16B load (compiler-generated sc0 sc1 + proper waitcnt): safe,
// used by the cross-XCD OUT role (R5-proven correct)
__device__ __forceinline__ bf16x8 ld8c(const u16* p) {
  union { bf16x8 v; u64 q[2]; } r;
  r.q[0] = __hip_atomic_load((const u64*)p,     __ATOMIC_RELAXED, __HIP_MEMORY_SCOPE_AGENT);
  r.q[1] = __hip_atomic_load((const u64*)p + 1, __ATOMIC_RELAXED, __HIP_MEMORY_SCOPE_AGENT);
  return r.v;
}
__device__ __forceinline__ f32x4 mfma(bf16x8 a, bf16x8 b, f32x4 c) {
  return __builtin_amdgcn_mfma_f32_16x16x32_bf16(a, b, c, 0, 0, 0);
}
__device__ __forceinline__ int ldslot(const int* s, int i) {
  return __hip_atomic_load(&s[i], __ATOMIC_RELAXED, __HIP_MEMORY_SCOPE_AGENT);
}
__device__ __forceinline__ void stslot(int* s, int i, int v) {
  __hip_atomic_store(&s[i], v, __ATOMIC_RELAXED, __HIP_MEMORY_SCOPE_AGENT);
}
// tick tag (k mod 3) in LSBs of bf16 elems 0,1 of each 8B granule.
// pat3 emits (0,0),(1,0),(0,1); pattern (1,1)=0x10001 is INVALID and is used
// as the init state of buffer 3 (the only buffer whose first occupant, tick 3,
// has tag 0 == the zero-init tag -- the R6/R7 startup race).
__device__ __forceinline__ u32 pat3(int t3) {
  return ((u32)t3 & 1u) | ((((u32)t3 >> 1) & 1u) << 16);
}
template<int N>
__device__ __forceinline__ bool tagsok(const bf16x8* ch, u32 pat) {
  bool ok = true;
#pragma unroll
  for (int c = 0; c < N; ++c) {
    union { bf16x8 v; u32 u[4]; } t; t.v = ch[c];
    ok = ok && ((t.u[0] & 0x10001u) == pat) && ((t.u[2] & 0x10001u) == pat);
  }
  return ok;
}
// SINGLE asm block: 8 sc0 loads (L1-bypass, local-L2 served) + the waitcnt.
// Outputs are defined only when the whole block retires -> no register-split
// hazard between issue and wait (the R6 bug).
__device__ __forceinline__ void ldw8_sc0(const u16* p, bf16x8* ch) {
  asm volatile(
      "global_load_dwordx4 %0, %8, off sc0\n\t"
      "global_load_dwordx4 %1, %8, off offset:64 sc0\n\t"
      "global_load_dwordx4 %2, %8, off offset:128 sc0\n\t"
      "global_load_dwordx4 %3, %8, off offset:192 sc0\n\t"
      "global_load_dwordx4 %4, %8, off offset:256 sc0\n\t"
      "global_load_dwordx4 %5, %8, off offset:320 sc0\n\t"
      "global_load_dwordx4 %6, %8, off offset:384 sc0\n\t"
      "global_load_dwordx4 %7, %8, off offset:448 sc0\n\t"
      "s_waitcnt vmcnt(0)"
      : "=&v"(ch[0]), "=&v"(ch[1]), "=&v"(ch[2]), "=&v"(ch[3]),
        "=&v"(ch[4]), "=&v"(ch[5]), "=&v"(ch[6]), "=&v"(ch[7])
      : "v"(p)
      : "memory");
}
__device__ __forceinline__ void ldw16_sc0(const u16* p0, const u16* p1, bf16x8* ch) {
  asm volatile(
      "global_load_dwordx4 %0, %16, off sc0\n\t"
      "global_load_dwordx4 %1, %16, off offset:64 sc0\n\t"
      "global_load_dwordx4 %2, %16, off offset:128 sc0\n\t"
      "global_load_dwordx4 %3, %16, off offset:192 sc0\n\t"
      "global_load_dwordx4 %4, %16, off offset:256 sc0\n\t"
      "global_load_dwordx4 %5, %16, off offset:320 sc0\n\t"
      "global_load_dwordx4 %6, %16, off offset:384 sc0\n\t"
      "global_load_dwordx4 %7, %16, off offset:448 sc0\n\t"
      "global_load_dwordx4 %8, %17, off sc0\n\t"
      "global_load_dwordx4 %9, %17, off offset:64 sc0\n\t"
      "global_load_dwordx4 %10, %17, off offset:128 sc0\n\t"
      "global_load_dwordx4 %11, %17, off offset:192 sc0\n\t"
      "global_load_dwordx4 %12, %17, off offset:256 sc0\n\t"
      "global_load_dwordx4 %13, %17, off offset:320 sc0\n\t"
      "global_load_dwordx4 %14, %17, off offset:384 sc0\n\t"
      "global_load_dwordx4 %15, %17, off offset:448 sc0\n\t"
      "s_waitcnt vmcnt(0)"
      : "=&v"(ch[0]), "=&v"(ch[1]), "=&v"(ch[2]), "=&v"(ch[3]),
        "=&v"(ch[4]), "=&v"(ch[5]), "=&v"(ch[6]), "=&v"(ch[7]),
        "=&v"(ch[8]), "=&v"(ch[9]), "=&v"(ch[10]), "=&v"(ch[11]),
        "=&v"(ch[12]), "=&v"(ch[13]), "=&v"(ch[14]), "=&v"(ch[15])
      : "v"(p0), "v"(p1)
      : "memory");
}
// poll until tags match; fast path = local L2; periodic agent acquire fence
// (L1+L2 invalidate) keeps wrong-XCD placement correct (slow but converging)
__device__ __forceinline__ void poll8_sc0(const u16* p, u32 pat, bf16x8* ch) {
  int spins = 0;
  for (;;) {
    ldw8_sc0(p, ch);
    if (__all(tagsok<8>(ch, pat))) break;
    ++spins;
    if ((spins & 31) == 31) __builtin_amdgcn_fence(__ATOMIC_ACQUIRE, "agent");
    else if (spins > 1) __builtin_amdgcn_s_sleep(1);
  }
  __asm__ volatile("" ::: "memory");
}
__device__ __forceinline__ void poll16_sc0(const u16* p0, const u16* p1, u32 pat, bf16x8* ch) {
  int spins = 0;
  for (;;) {
    ldw16_sc0(p0, p1, ch);
    if (__all(tagsok<8>(ch, pat) && tagsok<8>(ch + 8, pat))) break;
    ++spins;
    if ((spins & 31) == 31) __builtin_amdgcn_fence(__ATOMIC_ACQUIRE, "agent");
    else if (spins > 1) __builtin_amdgcn_s_sleep(1);
  }
  __asm__ volatile("" ::: "memory");
}
// tagged dual store: normal store (local XCD L2, fast intra-XCD visibility) +
// sc0 sc1 write-through (visible to remote-XCD agent loads). Same value both.
__device__ __forceinline__ void st_h_dual(u16* p, const float* h, int t3) {
  u16 a = (u16)((f2bf(h[0]) & ~1u) | ((u32)t3 & 1u));
  u16 b = (u16)((f2bf(h[1]) & ~1u) | (((u32)t3 >> 1) & 1u));
  u64 v = (u64)a | ((u64)b << 16) | ((u64)f2bf(h[2]) << 32) | ((u64)f2bf(h[3]) << 48);
  *(volatile u64*)p = v;
  asm volatile("global_store_dwordx2 %0, %1, off sc0 sc1" :: "v"(p), "v"(v) : "memory");
}
// amortized producer throttle on consumer watermarks (anti-dep, off critical path)
__device__ __forceinline__ void throttle(const int* slots, int baseA, int nA,
                                         int baseB, int nB, int k, int& bound) {
  if (bound >= k - 3) return;
  const int lane = threadIdx.x & 63;
  int idx = -1;
  if (lane < nA) idx = baseA + lane;
  else if (lane < nA + nB) idx = baseB + (lane - nA);
  for (;;) {
    int v = (idx >= 0) ? ldslot(slots, idx) : 0x7fffffff;
    if (__all(v >= k - 3)) { bound = __all(v >= k) ? k : (k - 3); break; }
    __builtin_amdgcn_s_sleep(2);
  }
}

// Placement (grid 256, xcd = blockIdx%8 round-robin heuristic, 1 block/CU):
//   XCD0: slots 0..15 L1-GRU g0 (32 units each), slots 16..31 L2-GRU g0
//   XCD1: same for batch group 1
//   XCD2: slots 0..3 OUT (16 batch each); all other blocks exit
// h1,h2: 4 bufs (k mod 4), tags k mod 3 -> alias at distance 12, throttle 3.
// Buffer 3 of each is init'd to the INVALID tag pattern (see pat3 comment).
// Watermarks: slots[0..31] = L2-GRU WGs, slots[32..35] = OUT WGs.
// MFMA 16x16x32 frags: A m=l15,k=q*8+j ; B n=l15,k=q*8+j ; C/D col=l15,row=q*4+r
__global__ __launch_bounds__(512, 1) void stackgru(
    const float* __restrict__ x,
    const float* __restrict__ wih1, const float* __restrict__ whh1,
    const float* __restrict__ bih1, const float* __restrict__ bhh1,
    const float* __restrict__ wih2, const float* __restrict__ whh2,
    const float* __restrict__ bih2, const float* __restrict__ bhh2,
    const float* __restrict__ wo1, const float* __restrict__ bo1,
    const float* __restrict__ wo2, const float* __restrict__ bo2,
    float* __restrict__ out, u16* __restrict__ hbuf, int* __restrict__ slots)
{
  __shared__ float red[2][2][3][3][64][4];   // 36 KB, sub-indexed per role
  const int xcd = blockIdx.x & 7, slot = blockIdx.x >> 3;
  const int tid = threadIdx.x;
  const int lane = tid & 63;
  const int w = tid >> 6;
  const int l15 = lane & 15;
  const int q = lane >> 4;

  u16* h1b = hbuf;                     // 4 * kBH
  u16* h2b = hbuf + 4 * kBH;           // 4 * kBH

  if (xcd <= 1 && slot < 16) {
    // ---------------- layer 1 (16 WGs on XCD g; 32 units, 32 batch each) ----
    const int g = xcd, b0 = g * 32;
    const int m = w & 1, bt = (w >> 1) & 1, kh = w >> 2;  // unit-tile, batch-tile, K-half
    const int un = slot * 32 + m * 16;
    const int bb = b0 + bt * 16 + l15;
    bf16x8 ahh[3][8];                           // 96 VGPRs w_hh1 frags
#pragma unroll
    for (int gg = 0; gg < 3; ++gg)
#pragma unroll
      for (int c = 0; c < 8; ++c)
        ahh[gg][c] = cvt8(whh1 + (gg * kH + un + l15) * kH + kh * 256 + c * 32 + q * 8);
    bf16x8 aih[3][2];
    float br[4], bz[4], bni[4], bnh[4], h1l[4];
    int bound = 0;
    if (kh == 0) {
#pragma unroll
      for (int gg = 0; gg < 3; ++gg)
#pragma unroll
        for (int c = 0; c < 2; ++c)
          aih[gg][c] = cvt8(wih1 + (gg * kH + un + l15) * kI + c * 32 + q * 8);
#pragma unroll
      for (int r = 0; r < 4; ++r) {
        int u = un + q * 4 + r;
        br[r]  = bih1[u]          + bhh1[u];
        bz[r]  = bih1[kH + u]     + bhh1[kH + u];
        bni[r] = bih1[2 * kH + u];
        bnh[r] = bhh1[2 * kH + u];
        h1l[r] = 0.0f;                  // fp32 master h1 lives in regs
      }
    }
    for (int k = 1; k <= kT; ++k) {
      const int t3 = k % 3, t3p = (k - 1) % 3;
      bf16x8 xf0, xf1;
      if (kh == 0) {                    // x prefetch (plain cached loads)
        const float* xs = x + (bb * kT + (k - 1)) * kI + q * 8;
        xf0 = cvt8(xs); xf1 = cvt8(xs + 32);
      }
      bf16x8 ch[8];
      poll8_sc0(h1b + ((k - 1) & 3) * kBH + bb * kH + kh * 256 + q * 8, pat3(t3p), ch);
      f32x4 a0 = {0,0,0,0}, a1 = {0,0,0,0}, a2 = {0,0,0,0};
#pragma unroll
      for (int c = 0; c < 8; ++c) {
        a0 = mfma(ahh[0][c], ch[c], a0);
        a1 = mfma(ahh[1][c], ch[c], a1);
        a2 = mfma(ahh[2][c], ch[c], a2);
      }
      f32x4 x0 = {0,0,0,0}, x1 = {0,0,0,0}, x2 = {0,0,0,0};
      if (kh == 1) {
#pragma unroll
        for (int r = 0; r < 4; ++r) {
          red[m][bt][0][0][lane][r] = a0[r];
          red[m][bt][0][1][lane][r] = a1[r];
          red[m][bt][0][2][lane][r] = a2[r];
        }
      } else {
        x0 = mfma(aih[0][0], xf0, x0); x0 = mfma(aih[0][1], xf1, x0);
        x1 = mfma(aih[1][0], xf0, x1); x1 = mfma(aih[1][1], xf1, x1);
        x2 = mfma(aih[2][0], xf0, x2); x2 = mfma(aih[2][1], xf1, x2);
        throttle(slots, g * 16, 16, 32 + g * 2, 2, k, bound);   // h1 anti-dep
      }
      __syncthreads();
      if (kh == 0) {
        float hnew[4];
#pragma unroll
        for (int r = 0; r < 4; ++r) {
          float gh0 = a0[r] + red[m][bt][0][0][lane][r];
          float gh1 = a1[r] + red[m][bt][0][1][lane][r];
          float gh2 = a2[r] + red[m][bt][0][2][lane][r];
          float rr = sigf(x0[r] + gh0 + br[r]);
          float zz = sigf(x1[r] + gh1 + bz[r]);
          float nn = tanhf_(x2[r] + bni[r] + rr * (gh2 + bnh[r]));
          float h  = (1.0f - zz) * nn + zz * h1l[r];
          h1l[r] = h; hnew[r] = h;
        }
        st_h_dual(h1b + (k & 3) * kBH + bb * kH + un + q * 4, hnew, t3);
      }
      __syncthreads();                  // protect red for next tick
    }
  } else if (xcd <= 1) {
    // ---------------- layer 2 (16 WGs on XCD g; 32 units, 32 batch each) ----
    const int g = xcd, b0 = g * 32, s16 = slot - 16;
    const int mat = w & 1, m = (w >> 1) & 1, kh = w >> 2;
    const int un = s16 * 32 + m * 16;
    const int bb0 = b0 + l15, bb1 = b0 + 16 + l15;
    const float* wsrc = mat ? whh2 : wih2;
    bf16x8 af[3][8];
#pragma unroll
    for (int gg = 0; gg < 3; ++gg)
#pragma unroll
      for (int c = 0; c < 8; ++c)
        af[gg][c] = cvt8(wsrc + (gg * kH + un + l15) * kH + kh * 256 + c * 32 + q * 8);
    const bool upd = (mat == 0 && kh == 0);
    float br[4], bz[4], bni[4], bnh[4], h2l[2][4];
    int bound = 0;
    if (upd) {
#pragma unroll
      for (int r = 0; r < 4; ++r) {
        int u = un + q * 4 + r;
        br[r]  = bih2[u]          + bhh2[u];
        bz[r]  = bih2[kH + u]     + bhh2[kH + u];
        bni[r] = bih2[2 * kH + u];
        bnh[r] = bhh2[2 * kH + u];
        h2l[0][r] = 0.0f; h2l[1][r] = 0.0f;
      }
    }
    for (int k = 1; k <= kT; ++k) {
      const int t3 = k % 3, t3p = (k - 1) % 3;
      const u16* base = (mat == 0) ? h1b + (k & 3) * kBH : h2b + ((k - 1) & 3) * kBH;
      const u32 pat = pat3(mat == 0 ? t3 : t3p);
      bf16x8 ch[16];
      poll16_sc0(base + bb0 * kH + kh * 256 + q * 8,
                 base + bb1 * kH + kh * 256 + q * 8, pat, ch);
      f32x4 A0[3] = {{0,0,0,0},{0,0,0,0},{0,0,0,0}};
      f32x4 A1[3] = {{0,0,0,0},{0,0,0,0},{0,0,0,0}};
#pragma unroll
      for (int c = 0; c < 8; ++c)
#pragma unroll
        for (int gg = 0; gg < 3; ++gg) {
          A0[gg] = mfma(af[gg][c], ch[c], A0[gg]);
          A1[gg] = mfma(af[gg][c], ch[8 + c], A1[gg]);
        }
      if (!upd) {
        const int s = mat * 2 + kh - 1;   // mat0kh1->0, mat1kh0->1, mat1kh1->2
#pragma unroll
        for (int gg = 0; gg < 3; ++gg)
#pragma unroll
          for (int r = 0; r < 4; ++r) {
            red[m][0][s][gg][lane][r] = A0[gg][r];
            red[m][1][s][gg][lane][r] = A1[gg][r];
          }
      } else {
        throttle(slots, 32 + g * 2, 2, 0, 0, k, bound);    // h2 anti-dep (OUT)
      }
      __syncthreads();
      if (tid == 0) stslot(slots, g * 16 + s16, k);        // inputs consumed
      if (upd) {
#pragma unroll
        for (int bt = 0; bt < 2; ++bt) {
          const f32x4* A = bt ? A1 : A0;
          float hnew[4];
#pragma unroll
          for (int r = 0; r < 4; ++r) {
            float gi0 = A[0][r] + red[m][bt][0][0][lane][r];
            float gi1 = A[1][r] + red[m][bt][0][1][lane][r];
            float gi2 = A[2][r] + red[m][bt][0][2][lane][r];
            float gh0 = red[m][bt][1][0][lane][r] + red[m][bt][2][0][lane][r];
            float gh1 = red[m][bt][1][1][lane][r] + red[m][bt][2][1][lane][r];
            float gh2 = red[m][bt][1][2][lane][r] + red[m][bt][2][2][lane][r];
            float rr = sigf(gi0 + gh0 + br[r]);
            float zz = sigf(gi1 + gh1 + bz[r]);
            float nn = tanhf_(gi2 + bni[r] + rr * (gh2 + bnh[r]));
            float h  = (1.0f - zz) * nn + zz * h2l[bt][r];
            h2l[bt][r] = h; hnew[r] = h;
          }
          st_h_dual(h2b + (k & 3) * kBH + (b0 + bt * 16 + l15) * kH + un + q * 4,
                    hnew, t3);
        }
      }
      __syncthreads();
    }
  } else if (xcd == 2 && slot < 4) {
    // ---------------- output head (4 WGs on XCD2, 16 batch each) ------------
    const int g3 = slot;
    const int bb = g3 * 16 + l15;
    const int mat = w & 1, khh = (w >> 1) & 1, rt = w >> 2;
    const float* wsel = mat ? wo2 : wo1;
    const int row = rt * 16 + l15;
    bf16x8 zf = {0,0,0,0,0,0,0,0};
    bf16x8 af[8];
#pragma unroll
    for (int c = 0; c < 8; ++c)
      af[c] = (row < kO) ? cvt8(wsel + row * kH + khh * 256 + c * 32 + q * 8) : zf;
    const bool fin = (mat == 0 && khh == 0);
    float bv1[4], bv2[4];
    if (fin) {
#pragma unroll
      for (int r = 0; r < 4; ++r) {
        int o = rt * 16 + q * 4 + r;
        bv1[r] = (o < kO) ? bo1[o] : 0.0f;
        bv2[r] = (o < kO) ? bo2[o] : 0.0f;
      }
    }
    const u16* hb = (mat == 0) ? h1b : h2b;
    bf16x8 ch[8];
    bool have = false;
    for (int k = 1; k <= kT; ++k) {
      const int t3 = k % 3;
      const u32 pat = pat3(t3);
      const u16* hs = hb + (k & 3) * kBH + bb * kH + khh * 256 + q * 8;
      if (!(have && __all(tagsok<8>(ch, pat)))) {
        int spins = 0;
        do {
#pragma unroll
          for (int c = 0; c < 8; ++c) ch[c] = ld8c(hs + c * 32);
          if ((++spins & 7) == 7) __builtin_amdgcn_s_sleep(1);
        } while (!__all(tagsok<8>(ch, pat)));
      }
      f32x4 a0 = {0,0,0,0};
#pragma unroll
      for (int c = 0; c < 8; ++c) a0 = mfma(af[c], ch[c], a0);
      if (k < kT) {                      // lookahead prefetch for tick k+1
        const u16* ns = hb + ((k + 1) & 3) * kBH + bb * kH + khh * 256 + q * 8;
#pragma unroll
        for (int c = 0; c < 8; ++c) ch[c] = ld8c(ns + c * 32);
        have = true;
      }
      if (!fin) {
        const int s = mat * 2 + khh - 1;
#pragma unroll
        for (int r = 0; r < 4; ++r) red[rt][0][s][0][lane][r] = a0[r];
      }
      __syncthreads();
      if (fin) {
        int o0 = rt * 16 + q * 4;
        if (o0 < kO) {
          float4 ov;
          ov.x = tanhf_(a0[0] + red[rt][0][0][0][lane][0] + bv1[0]) +
                 tanhf_(red[rt][0][1][0][lane][0] + red[rt][0][2][0][lane][0] + bv2[0]);
          ov.y = tanhf_(a0[1] + red[rt][0][0][0][lane][1] + bv1[1]) +
                 tanhf_(red[rt][0][1][0][lane][1] + red[rt][0][2][0][lane][1] + bv2[1]);
          ov.z = tanhf_(a0[2] + red[rt][0][0][0][lane][2] + bv1[2]) +
                 tanhf_(red[rt][0][1][0][lane][2] + red[rt][0][2][0][lane][2] + bv2[2]);
          ov.w = tanhf_(a0[3] + red[rt][0][0][0][lane][3] + bv1[3]) +
                 tanhf_(red[rt][0][1][0][lane][3] + red[rt][0][2][0][lane][3] + bv2[3]);
          *reinterpret_cast<float4*>(out + (bb * kT + (k - 1)) * kO + o0) = ov;
        }
      }
      if (tid == 0) stslot(slots, 32 + g3, k);
      __syncthreads();
    }
  }
}

extern "C" void kernel_launch(void* const* d_in, const int* in_sizes, int n_in,
                              void* d_out, int out_size, void* d_ws, size_t ws_size,
                              hipStream_t stream) {
  (void)in_sizes; (void)n_in; (void)out_size; (void)ws_size;
  // zero h buffers 0..2 (tag 0 == tick 0) + watermark slots; buffer 3 of each
  // h gets the INVALID tag pattern (byte 0x01 -> granule tag (1,1), which
  // pat3 never produces) to close the tick-3 startup race.
  hipMemsetAsync(d_ws, 0, kBarOff + 1024, stream);
  hipMemsetAsync((char*)d_ws + 3u * kBH * 2u, 0x01, kBH * 2u, stream);  // h1 buf3
  hipMemsetAsync((char*)d_ws + 7u * kBH * 2u, 0x01, kBH * 2u, stream);  // h2 buf3
  const float* x    = (const float*)d_in[0];
  const float* wih1 = (const float*)d_in[1];
  const float* whh1 = (const float*)d_in[2];
  const float* bih1 = (const float*)d_in[3];
  const float* bhh1 = (const float*)d_in[4];
  const float* wih2 = (const float*)d_in[5];
  const float* whh2 = (const float*)d_in[6];
  const float* bih2 = (const float*)d_in[7];
  const float* bhh2 = (const float*)d_in[8];
  const float* wo1  = (const float*)d_in[9];
  const float* bo1  = (const float*)d_in[10];
  const float* wo2  = (const float*)d_in[11];
  const float* bo2  = (const float*)d_in[12];
  float* out  = (float*)d_out;
  u16* hbuf   = (u16*)d_ws;
  int* slots  = (int*)((char*)d_ws + kBarOff);
  stackgru<<<dim3(256), dim3(512), 0, stream>>>(
      x, wih1, whh1, bih1, bhh1, wih2, whh2, bih2, bhh2,
      wo1, bo1, wo2, bo2, out, hbuf, slots);
}

// Round 9
// 31376.794 us; speedup vs baseline: 1.6105x; 1.6105x over previous
//
#include <hip/hip_runtime.h>

typedef unsigned short u16;
typedef unsigned int u32;
typedef unsigned long long u64;
typedef __attribute__((ext_vector_type(8))) short bf16x8;   // 8 bf16 = 4 VGPRs
typedef __attribute__((ext_vector_type(4))) float f32x4;

namespace {
constexpr int kT = 1024, kI = 64, kH = 512, kO = 24;
constexpr int kB = 64;
constexpr int kBH = kB * kH;                  // 32768 elems per h buffer (bf16)
// h1: 8 bufs, h2: 8 bufs (mod 8), tags mod 3
constexpr unsigned kBarOff = 16u * (unsigned)kBH * 2u;   // 1048576 B
// int-slot layout inside the control page (all zeroed each launch):
//   [0..31]  L2 consumption watermarks   [32..35] OUT watermarks
//   [64..71] per-XCD claim counters      [128..159] prod_h1 flags
//   [160..191] prod_h2 flags
}

__device__ __forceinline__ u16 f2bf(float f) {   // round-to-nearest-even
  union { float f; u32 u; } c; c.f = f;
  u32 u = c.u + 0x7FFFu + ((c.u >> 16) & 1u);
  return (u16)(u >> 16);
}
__device__ __forceinline__ float sigf(float x) { return 1.0f / (1.0f + __expf(-x)); }
__device__ __forceinline__ float tanhf_(float x) {
  float e = __expf(2.0f * x); return 1.0f - 2.0f / (e + 1.0f);  // safe at +-inf
}
__device__ __forceinline__ bf16x8 cvt8(const float* p) {  // fp32x8 -> bf16x8 (RNE)
  const float4 f0 = *reinterpret_cast<const float4*>(p);
  const float4 f1 = *reinterpret_cast<const float4*>(p + 4);
  bf16x8 r;
  r[0] = (short)f2bf(f0.x); r[1] = (short)f2bf(f0.y);
  r[2] = (short)f2bf(f0.z); r[3] = (short)f2bf(f0.w);
  r[4] = (short)f2bf(f1.x); r[5] = (short)f2bf(f1.y);
  r[6] = (short)f2bf(f1.z); r[7] = (short)f2bf(f1.w);
  return r;
}
// agent-coherent 16B load (compiler sc0 sc1 + waitcnt): cross-XCD (OUT role)
__device__ __forceinline__ bf16x8 ld8c(const u16* p) {
  union { bf16x8 v; u64 q[2]; } r;
  r.q[0] = __hip_atomic_load((const u64*)p,     __ATOMIC_RELAXED, __HIP_MEMORY_SCOPE_AGENT);
  r.q[1] = __hip_atomic_load((const u64*)p + 1, __ATOMIC_RELAXED, __HIP_MEMORY_SCOPE_AGENT);
  return r.v;
}
__device__ __forceinline__ f32x4 mfma(bf16x8 a, bf16x8 b, f32x4 c) {
  return __builtin_amdgcn_mfma_f32_16x16x32_bf16(a, b, c, 0, 0, 0);
}
__device__ __forceinline__ int ldslot(const int* s, int i) {
  return __hip_atomic_load(&s[i], __ATOMIC_RELAXED, __HIP_MEMORY_SCOPE_AGENT);
}
__device__ __forceinline__ void stslot(int* s, int i, int v) {
  __hip_atomic_store(&s[i], v, __ATOMIC_RELAXED, __HIP_MEMORY_SCOPE_AGENT);
}
// tick tag (k mod 3) in LSBs of bf16 elems 0,1 of each 8B granule.
// pat3 emits (0,0),(1,0),(0,1); (1,1) is INVALID (init state of bufs 3,6).
__device__ __forceinline__ u32 pat3(int t3) {
  return ((u32)t3 & 1u) | ((((u32)t3 >> 1) & 1u) << 16);
}
template<int N>
__device__ __forceinline__ bool tagsok(const bf16x8* ch, u32 pat) {
  bool ok = true;
#pragma unroll
  for (int c = 0; c < N; ++c) {
    union { bf16x8 v; u32 u[4]; } t; t.v = ch[c];
    ok = ok && ((t.u[0] & 0x10001u) == pat) && ((t.u[2] & 0x10001u) == pat);
  }
  return ok;
}
// SINGLE asm block: loads + waitcnt together (no issue/wait register seam).
__device__ __forceinline__ void ldw8_sc0(const u16* p, bf16x8* ch) {
  asm volatile(
      "global_load_dwordx4 %0, %8, off sc0\n\t"
      "global_load_dwordx4 %1, %8, off offset:64 sc0\n\t"
      "global_load_dwordx4 %2, %8, off offset:128 sc0\n\t"
      "global_load_dwordx4 %3, %8, off offset:192 sc0\n\t"
      "global_load_dwordx4 %4, %8, off offset:256 sc0\n\t"
      "global_load_dwordx4 %5, %8, off offset:320 sc0\n\t"
      "global_load_dwordx4 %6, %8, off offset:384 sc0\n\t"
      "global_load_dwordx4 %7, %8, off offset:448 sc0\n\t"
      "s_waitcnt vmcnt(0)"
      : "=&v"(ch[0]), "=&v"(ch[1]), "=&v"(ch[2]), "=&v"(ch[3]),
        "=&v"(ch[4]), "=&v"(ch[5]), "=&v"(ch[6]), "=&v"(ch[7])
      : "v"(p)
      : "memory");
}
__device__ __forceinline__ void ldw16_sc0(const u16* p0, const u16* p1, bf16x8* ch) {
  asm volatile(
      "global_load_dwordx4 %0, %16, off sc0\n\t"
      "global_load_dwordx4 %1, %16, off offset:64 sc0\n\t"
      "global_load_dwordx4 %2, %16, off offset:128 sc0\n\t"
      "global_load_dwordx4 %3, %16, off offset:192 sc0\n\t"
      "global_load_dwordx4 %4, %16, off offset:256 sc0\n\t"
      "global_load_dwordx4 %5, %16, off offset:320 sc0\n\t"
      "global_load_dwordx4 %6, %16, off offset:384 sc0\n\t"
      "global_load_dwordx4 %7, %16, off offset:448 sc0\n\t"
      "global_load_dwordx4 %8, %17, off sc0\n\t"
      "global_load_dwordx4 %9, %17, off offset:64 sc0\n\t"
      "global_load_dwordx4 %10, %17, off offset:128 sc0\n\t"
      "global_load_dwordx4 %11, %17, off offset:192 sc0\n\t"
      "global_load_dwordx4 %12, %17, off offset:256 sc0\n\t"
      "global_load_dwordx4 %13, %17, off offset:320 sc0\n\t"
      "global_load_dwordx4 %14, %17, off offset:384 sc0\n\t"
      "global_load_dwordx4 %15, %17, off offset:448 sc0\n\t"
      "s_waitcnt vmcnt(0)"
      : "=&v"(ch[0]), "=&v"(ch[1]), "=&v"(ch[2]), "=&v"(ch[3]),
        "=&v"(ch[4]), "=&v"(ch[5]), "=&v"(ch[6]), "=&v"(ch[7]),
        "=&v"(ch[8]), "=&v"(ch[9]), "=&v"(ch[10]), "=&v"(ch[11]),
        "=&v"(ch[12]), "=&v"(ch[13]), "=&v"(ch[14]), "=&v"(ch[15])
      : "v"(p0), "v"(p1)
      : "memory");
}
// flag poll, intra-XCD: lanes read 8 producer flags (lane&7) from local L2.
__device__ __forceinline__ void waitflags8_sc0(const int* f, int thr) {
  const int* p = f + ((threadIdx.x & 63) & 7);
  int spins = 0;
  for (;;) {
    int v;
    asm volatile("global_load_dword %0, %1, off sc0\n\ts_waitcnt vmcnt(0)"
                 : "=v"(v) : "v"(p) : "memory");
    if (__all(v >= thr)) break;
    ++spins;
    if ((spins & 255) == 255) __builtin_amdgcn_fence(__ATOMIC_ACQUIRE, "agent");
    else if (spins > 4) __builtin_amdgcn_s_sleep(1);
  }
}
// flag poll, cross-XCD (agent scope)
__device__ __forceinline__ void waitflags8_agent(const int* f, int thr) {
  const int* p = f + ((threadIdx.x & 63) & 7);
  int spins = 0;
  for (;;) {
    int v = __hip_atomic_load(p, __ATOMIC_RELAXED, __HIP_MEMORY_SCOPE_AGENT);
    if (__all(v >= thr)) break;
    if ((++spins & 7) == 7) __builtin_amdgcn_s_sleep(2);
  }
}
// data load after flags; tag re-validate is belt-and-braces (flag implies data
// at local L2 intra-XCD; rare retries cross-XCD while sc1 data lands at L3)
__device__ __forceinline__ void data8_sc0(const u16* p, u32 pat, bf16x8* ch) {
  int spins = 0;
  for (;;) {
    ldw8_sc0(p, ch);
    if (__all(tagsok<8>(ch, pat))) break;
    if ((++spins & 31) == 31) __builtin_amdgcn_fence(__ATOMIC_ACQUIRE, "agent");
  }
  __asm__ volatile("" ::: "memory");
}
__device__ __forceinline__ void data16_sc0(const u16* p0, const u16* p1, u32 pat, bf16x8* ch) {
  int spins = 0;
  for (;;) {
    ldw16_sc0(p0, p1, ch);
    if (__all(tagsok<8>(ch, pat) && tagsok<8>(ch + 8, pat))) break;
    if ((++spins & 31) == 31) __builtin_amdgcn_fence(__ATOMIC_ACQUIRE, "agent");
  }
  __asm__ volatile("" ::: "memory");
}
// tagged dual store: normal store (local XCD L2) + sc0 sc1 write-through
__device__ __forceinline__ void st_h_dual(u16* p, const float* h, int t3) {
  u16 a = (u16)((f2bf(h[0]) & ~1u) | ((u32)t3 & 1u));
  u16 b = (u16)((f2bf(h[1]) & ~1u) | (((u32)t3 >> 1) & 1u));
  u64 v = (u64)a | ((u64)b << 16) | ((u64)f2bf(h[2]) << 32) | ((u64)f2bf(h[3]) << 48);
  *(volatile u64*)p = v;
  asm volatile("global_store_dwordx2 %0, %1, off sc0 sc1" :: "v"(p), "v"(v) : "memory");
}
// progress-flag dual post (call AFTER __syncthreads drained the data stores)
__device__ __forceinline__ void postflag(int* p, int v) {
  *(volatile int*)p = v;
  asm volatile("global_store_dword %0, %1, off sc0 sc1" :: "v"(p), "v"(v) : "memory");
}
// amortized producer throttle: consumers' watermarks must reach k-7 before
// overwriting the mod-8 buffer slot of tick k-8 (off critical path)
__device__ __forceinline__ void throttle(const int* slots, int baseA, int nA,
                                         int baseB, int nB, int k, int& bound) {
  if (bound >= k - 7) return;
  const int lane = threadIdx.x & 63;
  int idx = -1;
  if (lane < nA) idx = baseA + lane;
  else if (lane < nA + nB) idx = baseB + (lane - nA);
  for (;;) {
    int v = (idx >= 0) ? ldslot(slots, idx) : 0x7fffffff;
    if (__all(v >= k - 7)) { bound = __all(v >= k) ? k : (k - 7); break; }
    __builtin_amdgcn_s_sleep(2);
  }
}

// Roles claimed at runtime by physical XCD (s_getreg HW_REG_XCC_ID, m09):
//   XCD0: claim 0..15 -> L1-g0 (32 units x 32 batch), 16..31 -> L2-g0
//   XCD1: same for batch group 1;  XCD2: claim 0..3 -> OUT; others exit.
// Grid 256, LDS-padded >80KB so 1 block/CU -> exactly 32 blocks per XCD.
// Intra-XCD handoff: normal stores + sc0 loads via the shared local L2.
// Cross-XCD (OUT only): sc1 write-through + agent loads via L3.
// h1,h2: 8 bufs (k mod 8), tags k mod 3; bufs 3,6 init'd to invalid tag.
__global__ __launch_bounds__(512, 1) void stackgru(
    const float* __restrict__ x,
    const float* __restrict__ wih1, const float* __restrict__ whh1,
    const float* __restrict__ bih1, const float* __restrict__ bhh1,
    const float* __restrict__ wih2, const float* __restrict__ whh2,
    const float* __restrict__ bih2, const float* __restrict__ bhh2,
    const float* __restrict__ wo1, const float* __restrict__ bo1,
    const float* __restrict__ wo2, const float* __restrict__ bo2,
    float* __restrict__ out, u16* __restrict__ hbuf, int* __restrict__ slots)
{
  __shared__ float red[2][2][3][3][64][4];   // 36 KB
  __shared__ char lds_pad[46080];            // force 1 block/CU (36+45 KB > 80 KB)
  __shared__ int role_sh;
  const int tid = threadIdx.x;
  if (blockIdx.x == 0xFFFFFFu) lds_pad[tid] = 1;   // keep pad allocated
  int* claim  = slots + 64;
  int* prodh1 = slots + 128;
  int* prodh2 = slots + 160;
  if (tid == 0) {
    u32 xcc;
    asm volatile("s_getreg_b32 %0, hwreg(HW_REG_XCC_ID)" : "=s"(xcc));
    xcc &= 7u;
    int s = atomicAdd(&claim[xcc], 1);
    role_sh = ((int)xcc << 8) | s;
  }
  __syncthreads();
  const int xcd = role_sh >> 8, slot = role_sh & 255;
  const int lane = tid & 63;
  const int w = tid >> 6;
  const int l15 = lane & 15;
  const int q = lane >> 4;

  u16* h1b = hbuf;                     // 8 * kBH
  u16* h2b = hbuf + 8 * kBH;           // 8 * kBH

  if (xcd <= 1 && slot < 16) {
    // ---------------- layer 1 (16 WGs on this XCD; 32 units, 32 batch) -----
    const int g = xcd, b0 = g * 32;
    const int m = w & 1, bt = (w >> 1) & 1, kh = w >> 2;
    const int un = slot * 32 + m * 16;
    const int bb = b0 + bt * 16 + l15;
    bf16x8 ahh[3][8];                           // 96 VGPRs w_hh1 frags
#pragma unroll
    for (int gg = 0; gg < 3; ++gg)
#pragma unroll
      for (int c = 0; c < 8; ++c)
        ahh[gg][c] = cvt8(whh1 + (gg * kH + un + l15) * kH + kh * 256 + c * 32 + q * 8);
    bf16x8 aih[3][2];
    float br[4], bz[4], bni[4], bnh[4], h1l[4];
    int bound = 0;
    if (kh == 0) {
#pragma unroll
      for (int gg = 0; gg < 3; ++gg)
#pragma unroll
        for (int c = 0; c < 2; ++c)
          aih[gg][c] = cvt8(wih1 + (gg * kH + un + l15) * kI + c * 32 + q * 8);
#pragma unroll
      for (int r = 0; r < 4; ++r) {
        int u = un + q * 4 + r;
        br[r]  = bih1[u]          + bhh1[u];
        bz[r]  = bih1[kH + u]     + bhh1[kH + u];
        bni[r] = bih1[2 * kH + u];
        bnh[r] = bhh1[2 * kH + u];
        h1l[r] = 0.0f;                  // fp32 master h1 lives in regs
      }
    }
    for (int k = 1; k <= kT; ++k) {
      const int t3 = k % 3, t3p = (k - 1) % 3;
      bf16x8 xf0, xf1;
      if (kh == 0) {
        const float* xs = x + (bb * kT + (k - 1)) * kI + q * 8;
        xf0 = cvt8(xs); xf1 = cvt8(xs + 32);
      }
      waitflags8_sc0(prodh1 + g * 16 + kh * 8, k - 1);
      bf16x8 ch[8];
      data8_sc0(h1b + ((k - 1) & 7) * kBH + bb * kH + kh * 256 + q * 8, pat3(t3p), ch);
      f32x4 a0 = {0,0,0,0}, a1 = {0,0,0,0}, a2 = {0,0,0,0};
#pragma unroll
      for (int c = 0; c < 8; ++c) {
        a0 = mfma(ahh[0][c], ch[c], a0);
        a1 = mfma(ahh[1][c], ch[c], a1);
        a2 = mfma(ahh[2][c], ch[c], a2);
      }
      f32x4 x0 = {0,0,0,0}, x1 = {0,0,0,0}, x2 = {0,0,0,0};
      if (kh == 1) {
#pragma unroll
        for (int r = 0; r < 4; ++r) {
          red[m][bt][0][0][lane][r] = a0[r];
          red[m][bt][0][1][lane][r] = a1[r];
          red[m][bt][0][2][lane][r] = a2[r];
        }
      } else {
        x0 = mfma(aih[0][0], xf0, x0); x0 = mfma(aih[0][1], xf1, x0);
        x1 = mfma(aih[1][0], xf0, x1); x1 = mfma(aih[1][1], xf1, x1);
        x2 = mfma(aih[2][0], xf0, x2); x2 = mfma(aih[2][1], xf1, x2);
        throttle(slots, g * 16, 16, 32 + g * 2, 2, k, bound);   // h1 anti-dep
      }
      __syncthreads();
      if (kh == 0) {
        float hnew[4];
#pragma unroll
        for (int r = 0; r < 4; ++r) {
          float gh0 = a0[r] + red[m][bt][0][0][lane][r];
          float gh1 = a1[r] + red[m][bt][0][1][lane][r];
          float gh2 = a2[r] + red[m][bt][0][2][lane][r];
          float rr = sigf(x0[r] + gh0 + br[r]);
          float zz = sigf(x1[r] + gh1 + bz[r]);
          float nn = tanhf_(x2[r] + bni[r] + rr * (gh2 + bnh[r]));
          float h  = (1.0f - zz) * nn + zz * h1l[r];
          h1l[r] = h; hnew[r] = h;
        }
        st_h_dual(h1b + (k & 7) * kBH + bb * kH + un + q * 4, hnew, t3);
      }
      __syncthreads();                  // drains ALL waves' h stores; guards red
      if (tid == 0) postflag(&prodh1[g * 16 + slot], k);
    }
  } else if (xcd <= 1) {
    // ---------------- layer 2 (16 WGs on this XCD; 32 units, 32 batch) -----
    const int g = xcd, b0 = g * 32, s16 = slot - 16;
    const int mat = w & 1, m = (w >> 1) & 1, kh = w >> 2;
    const int un = s16 * 32 + m * 16;
    const int bb0 = b0 + l15, bb1 = b0 + 16 + l15;
    const float* wsrc = mat ? whh2 : wih2;
    bf16x8 af[3][8];
#pragma unroll
    for (int gg = 0; gg < 3; ++gg)
#pragma unroll
      for (int c = 0; c < 8; ++c)
        af[gg][c] = cvt8(wsrc + (gg * kH + un + l15) * kH + kh * 256 + c * 32 + q * 8);
    const bool upd = (mat == 0 && kh == 0);
    float br[4], bz[4], bni[4], bnh[4], h2l[2][4];
    int bound = 0;
    if (upd) {
#pragma unroll
      for (int r = 0; r < 4; ++r) {
        int u = un + q * 4 + r;
        br[r]  = bih2[u]          + bhh2[u];
        bz[r]  = bih2[kH + u]     + bhh2[kH + u];
        bni[r] = bih2[2 * kH + u];
        bnh[r] = bhh2[2 * kH + u];
        h2l[0][r] = 0.0f; h2l[1][r] = 0.0f;
      }
    }
    for (int k = 1; k <= kT; ++k) {
      const int t3 = k % 3, t3p = (k - 1) % 3;
      if (mat == 0) waitflags8_sc0(prodh1 + g * 16 + kh * 8, k);
      else          waitflags8_sc0(prodh2 + g * 16 + kh * 8, k - 1);
      const u16* base = (mat == 0) ? h1b + (k & 7) * kBH : h2b + ((k - 1) & 7) * kBH;
      const u32 pat = pat3(mat == 0 ? t3 : t3p);
      bf16x8 ch[16];
      data16_sc0(base + bb0 * kH + kh * 256 + q * 8,
                 base + bb1 * kH + kh * 256 + q * 8, pat, ch);
      f32x4 A0[3] = {{0,0,0,0},{0,0,0,0},{0,0,0,0}};
      f32x4 A1[3] = {{0,0,0,0},{0,0,0,0},{0,0,0,0}};
#pragma unroll
      for (int c = 0; c < 8; ++c)
#pragma unroll
        for (int gg = 0; gg < 3; ++gg) {
          A0[gg] = mfma(af[gg][c], ch[c], A0[gg]);
          A1[gg] = mfma(af[gg][c], ch[8 + c], A1[gg]);
        }
      if (!upd) {
        const int s = mat * 2 + kh - 1;   // mat0kh1->0, mat1kh0->1, mat1kh1->2
#pragma unroll
        for (int gg = 0; gg < 3; ++gg)
#pragma unroll
          for (int r = 0; r < 4; ++r) {
            red[m][0][s][gg][lane][r] = A0[gg][r];
            red[m][1][s][gg][lane][r] = A1[gg][r];
          }
      } else {
        throttle(slots, 32 + g * 2, 2, 0, 0, k, bound);    // h2 anti-dep (OUT)
      }
      __syncthreads();
      if (tid == 0) stslot(slots, g * 16 + s16, k);        // inputs consumed
      if (upd) {
#pragma unroll
        for (int bt = 0; bt < 2; ++bt) {
          const f32x4* A = bt ? A1 : A0;
          float hnew[4];
#pragma unroll
          for (int r = 0; r < 4; ++r) {
            float gi0 = A[0][r] + red[m][bt][0][0][lane][r];
            float gi1 = A[1][r] + red[m][bt][0][1][lane][r];
            float gi2 = A[2][r] + red[m][bt][0][2][lane][r];
            float gh0 = red[m][bt][1][0][lane][r] + red[m][bt][2][0][lane][r];
            float gh1 = red[m][bt][1][1][lane][r] + red[m][bt][2][1][lane][r];
            float gh2 = red[m][bt][1][2][lane][r] + red[m][bt][2][2][lane][r];
            float rr = sigf(gi0 + gh0 + br[r]);
            float zz = sigf(gi1 + gh1 + bz[r]);
            float nn = tanhf_(gi2 + bni[r] + rr * (gh2 + bnh[r]));
            float h  = (1.0f - zz) * nn + zz * h2l[bt][r];
            h2l[bt][r] = h; hnew[r] = h;
          }
          st_h_dual(h2b + (k & 7) * kBH + (b0 + bt * 16 + l15) * kH + un + q * 4,
                    hnew, t3);
        }
      }
      __syncthreads();                  // drains upd stores; guards red
      if (tid == 0) postflag(&prodh2[g * 16 + s16], k);
    }
  } else if (xcd == 2 && slot < 4) {
    // ---------------- output head (4 WGs on XCD2, 16 batch each) -----------
    const int g3 = slot, g = g3 >> 1;
    const int bb = g3 * 16 + l15;
    const int mat = w & 1, khh = (w >> 1) & 1, rt = w >> 2;
    const float* wsel = mat ? wo2 : wo1;
    const int row = rt * 16 + l15;
    bf16x8 zf = {0,0,0,0,0,0,0,0};
    bf16x8 af[8];
#pragma unroll
    for (int c = 0; c < 8; ++c)
      af[c] = (row < kO) ? cvt8(wsel + row * kH + khh * 256 + c * 32 + q * 8) : zf;
    const bool fin = (mat == 0 && khh == 0);
    float bv1[4], bv2[4];
    if (fin) {
#pragma unroll
      for (int r = 0; r < 4; ++r) {
        int o = rt * 16 + q * 4 + r;
        bv1[r] = (o < kO) ? bo1[o] : 0.0f;
        bv2[r] = (o < kO) ? bo2[o] : 0.0f;
      }
    }
    const u16* hb = (mat == 0) ? h1b : h2b;
    const int* pf = (mat == 0) ? prodh1 : prodh2;
    for (int k = 1; k <= kT; ++k) {
      const u32 pat = pat3(k % 3);
      waitflags8_agent(pf + g * 16 + khh * 8, k);
      const u16* hs = hb + (k & 7) * kBH + bb * kH + khh * 256 + q * 8;
      bf16x8 ch[8];
      int spins = 0;
      for (;;) {       // data may trail the flag to L3 slightly: tag-validate
#pragma unroll
        for (int c = 0; c < 8; ++c) ch[c] = ld8c(hs + c * 32);
        if (__all(tagsok<8>(ch, pat))) break;
        if ((++spins & 7) == 7) __builtin_amdgcn_s_sleep(1);
      }
      f32x4 a0 = {0,0,0,0};
#pragma unroll
      for (int c = 0; c < 8; ++c) a0 = mfma(af[c], ch[c], a0);
      if (!fin) {
        const int s = mat * 2 + khh - 1;
#pragma unroll
        for (int r = 0; r < 4; ++r) red[rt][0][s][0][lane][r] = a0[r];
      }
      __syncthreads();
      if (fin) {
        int o0 = rt * 16 + q * 4;
        if (o0 < kO) {
          float4 ov;
          ov.x = tanhf_(a0[0] + red[rt][0][0][0][lane][0] + bv1[0]) +
                 tanhf_(red[rt][0][1][0][lane][0] + red[rt][0][2][0][lane][0] + bv2[0]);
          ov.y = tanhf_(a0[1] + red[rt][0][0][0][lane][1] + bv1[1]) +
                 tanhf_(red[rt][0][1][0][lane][1] + red[rt][0][2][0][lane][1] + bv2[1]);
          ov.z = tanhf_(a0[2] + red[rt][0][0][0][lane][2] + bv1[2]) +
                 tanhf_(red[rt][0][1][0][lane][2] + red[rt][0][2][0][lane][2] + bv2[2]);
          ov.w = tanhf_(a0[3] + red[rt][0][0][0][lane][3] + bv1[3]) +
                 tanhf_(red[rt][0][1][0][lane][3] + red[rt][0][2][0][lane][3] + bv2[3]);
          *reinterpret_cast<float4*>(out + (bb * kT + (k - 1)) * kO + o0) = ov;
        }
      }
      if (tid == 0) stslot(slots, 32 + g3, k);
      __syncthreads();
    }
  }
}

extern "C" void kernel_launch(void* const* d_in, const int* in_sizes, int n_in,
                              void* d_out, int out_size, void* d_ws, size_t ws_size,
                              hipStream_t stream) {
  (void)in_sizes; (void)n_in; (void)out_size; (void)ws_size;
  // zero h buffers + control page; invalid-tag init for bufs 3,6 of h1 & h2
  // (first-read ticks with t%3==0 that would match the zero-init tag)
  hipMemsetAsync(d_ws, 0, kBarOff + 1024, stream);
  hipMemsetAsync((char*)d_ws + 3u  * kBH * 2u, 0x01, kBH * 2u, stream);  // h1 buf3
  hipMemsetAsync((char*)d_ws + 6u  * kBH * 2u, 0x01, kBH * 2u, stream);  // h1 buf6
  hipMemsetAsync((char*)d_ws + 11u * kBH * 2u, 0x01, kBH * 2u, stream);  // h2 buf3
  hipMemsetAsync((char*)d_ws + 14u * kBH * 2u, 0x01, kBH * 2u, stream);  // h2 buf6
  const float* x    = (const float*)d_in[0];
  const float* wih1 = (const float*)d_in[1];
  const float* whh1 = (const float*)d_in[2];
  const float* bih1 = (const float*)d_in[3];
  const float* bhh1 = (const float*)d_in[4];
  const float* wih2 = (const float*)d_in[5];
  const float* whh2 = (const float*)d_in[6];
  const float* bih2 = (const float*)d_in[7];
  const float* bhh2 = (const float*)d_in[8];
  const float* wo1  = (const float*)d_in[9];
  const float* bo1  = (const float*)d_in[10];
  const float* wo2  = (const float*)d_in[11];
  const float* bo2  = (const float*)d_in[12];
  float* out  = (float*)d_out;
  u16* hbuf   = (u16*)d_ws;
  int* slots  = (int*)((char*)d_ws + kBarOff);
  stackgru<<<dim3(256), dim3(512), 0, stream>>>(
      x, wih1, whh1, bih1, bhh1, wih2, whh2, bih2, bhh2,
      wo1, bo1, wo2, bo2, out, hbuf, slots);
}

// Round 10
// 6057.472 us; speedup vs baseline: 8.3422x; 5.1798x over previous
//
#include <hip/hip_runtime.h>

typedef unsigned short u16;
typedef unsigned int u32;
typedef unsigned long long u64;
typedef __attribute__((ext_vector_type(8))) short bf16x8;   // 8 bf16 = 4 VGPRs
typedef __attribute__((ext_vector_type(4))) float f32x4;

namespace {
constexpr int kT = 1024, kI = 64, kH = 512, kO = 24;
constexpr int kBH = 64 * kH;                  // 32768 elems per h buffer (bf16)
constexpr int kNWG = 132;                     // 64 L1 + 64 L2 + 4 OUT
// h1: 4 bufs, h2: 4 bufs (k mod 4), tags k mod 3, buf3 invalid-init
constexpr unsigned kBarOff = 8u * (unsigned)kBH * 2u;   // 524288 B
// control ints at kBarOff: [0..63] flagL1, [64..127] flagL2, [128..131] flagOUT
}

__device__ __forceinline__ u16 f2bf(float f) {   // round-to-nearest-even
  union { float f; u32 u; } c; c.f = f;
  u32 u = c.u + 0x7FFFu + ((c.u >> 16) & 1u);
  return (u16)(u >> 16);
}
__device__ __forceinline__ float sigf(float x) { return 1.0f / (1.0f + __expf(-x)); }
__device__ __forceinline__ float tanhf_(float x) {
  float e = __expf(2.0f * x); return 1.0f - 2.0f / (e + 1.0f);  // safe at +-inf
}
__device__ __forceinline__ bf16x8 cvt8(const float* p) {  // fp32x8 -> bf16x8 (RNE)
  const float4 f0 = *reinterpret_cast<const float4*>(p);
  const float4 f1 = *reinterpret_cast<const float4*>(p + 4);
  bf16x8 r;
  r[0] = (short)f2bf(f0.x); r[1] = (short)f2bf(f0.y);
  r[2] = (short)f2bf(f0.z); r[3] = (short)f2bf(f0.w);
  r[4] = (short)f2bf(f1.x); r[5] = (short)f2bf(f1.y);
  r[6] = (short)f2bf(f1.z); r[7] = (short)f2bf(f1.w);
  return r;
}
// agent-coherent 16B load (compiler emits sc0 sc1 + waitcnt; R5-proven)
__device__ __forceinline__ bf16x8 ld8c(const u16* p) {
  union { bf16x8 v; u64 q[2]; } r;
  r.q[0] = __hip_atomic_load((const u64*)p,     __ATOMIC_RELAXED, __HIP_MEMORY_SCOPE_AGENT);
  r.q[1] = __hip_atomic_load((const u64*)p + 1, __ATOMIC_RELAXED, __HIP_MEMORY_SCOPE_AGENT);
  return r.v;
}
__device__ __forceinline__ f32x4 mfma(bf16x8 a, bf16x8 b, f32x4 c) {
  return __builtin_amdgcn_mfma_f32_16x16x32_bf16(a, b, c, 0, 0, 0);
}
__device__ __forceinline__ int ldflag(const int* s, int i) {
  return __hip_atomic_load(&s[i], __ATOMIC_RELAXED, __HIP_MEMORY_SCOPE_AGENT);
}
__device__ __forceinline__ void stflag(int* s, int i, int v) {
  __hip_atomic_store(&s[i], v, __ATOMIC_RELAXED, __HIP_MEMORY_SCOPE_AGENT);
}
// tick tag (k mod 3) in LSBs of bf16 elems 0,1 of each 8B granule.
// pat3 emits (0,0),(1,0),(0,1); (1,1) is INVALID = init of buf 3 (its first
// occupant, tick 3, has tag 0 which would match zero-init -- R8-proven fix).
__device__ __forceinline__ u32 pat3(int t3) {
  return ((u32)t3 & 1u) | ((((u32)t3 >> 1) & 1u) << 16);
}
template<int N>
__device__ __forceinline__ bool tagsok(const bf16x8* ch, u32 pat) {
  bool ok = true;
#pragma unroll
  for (int c = 0; c < N; ++c) {
    union { bf16x8 v; u32 u[4]; } t; t.v = ch[c];
    ok = ok && ((t.u[0] & 0x10001u) == pat) && ((t.u[2] & 0x10001u) == pat);
  }
  return ok;
}
// cheap flag poll: each lane one 4B agent load (64 B/wave/iter vs 8-16 KB for
// data polls -- the R5 congestion fix). idx is per-lane.
__device__ __forceinline__ void waitflag(const int* f, int idx, int thr) {
  int spins = 0;
  for (;;) {
    int v = ldflag(f, idx);
    if (__all(v >= thr)) break;
    if ((++spins & 3) == 3) __builtin_amdgcn_s_sleep(1);
  }
}
// data fetch after flag; tag-validated (flag/data may reorder across IC slices)
template<int N>
__device__ __forceinline__ void dataN(const u16* p, u32 pat, bf16x8* ch) {
  int spins = 0;
  for (;;) {
#pragma unroll
    for (int c = 0; c < N; ++c) ch[c] = ld8c(p + c * 32);
    if (__all(tagsok<N>(ch, pat))) break;
    if ((++spins & 7) == 7) __builtin_amdgcn_s_sleep(1);
  }
  __asm__ volatile("" ::: "memory");
}
// tagged h store: 4 bf16 + 2 tag bits, ONE agent-scope atomic 8B store
__device__ __forceinline__ void st_h(u16* p, const float* h, int t3) {
  u16 a = (u16)((f2bf(h[0]) & ~1u) | ((u32)t3 & 1u));
  u16 b = (u16)((f2bf(h[1]) & ~1u) | (((u32)t3 >> 1) & 1u));
  u64 v = (u64)a | ((u64)b << 16) | ((u64)f2bf(h[2]) << 32) | ((u64)f2bf(h[3]) << 48);
  __hip_atomic_store((u64*)p, v, __ATOMIC_RELAXED, __HIP_MEMORY_SCOPE_AGENT);
}
// amortized producer throttle: consumers >= k-3 before overwriting tick k-4
// (mod-4 buffers; alias distance 4; skew bound verified in journal R10)
__device__ __forceinline__ void throttle(const int* f, int idx, bool act,
                                         int k, int& bound) {
  if (bound >= k - 3) return;
  for (;;) {
    int v = act ? ldflag(f, idx) : 0x7fffffff;
    if (__all(v >= k - 3)) { bound = __all(v >= k) ? k : (k - 3); break; }
    __builtin_amdgcn_s_sleep(2);
  }
}

// Roles (132 WGs x 512 threads, free-running, flag+tag dataflow, all agent/L3):
//   wg   0..63 : layer-1 GRU. u0=(wg&31)*16 units, b0=(wg>>5)*32 batch.
//                waves: ntl(2 batch-16s) x kh(4 K-quarters). tick k -> h1[k]
//   wg  64..127: layer-2 GRU. waves: ntl(2) x mat(2) x kh(2 K-halves). -> h2[k]
//   wg 128..131: output head, 16 batch each. tick k -> out[k-1]
// flagL1/L2[wg]=k posts AFTER the tick-k h stores drained (2nd barrier).
// flagL2>=k also certifies h1[k] consumed (L2 reads h1[k] in tick k).
// MFMA 16x16x32 frags: A m=l15,k=q*8+j ; B n=l15,k=q*8+j ; C/D col=l15,row=q*4+r
__global__ __launch_bounds__(512, 1) void stackgru(
    const float* __restrict__ x,
    const float* __restrict__ wih1, const float* __restrict__ whh1,
    const float* __restrict__ bih1, const float* __restrict__ bhh1,
    const float* __restrict__ wih2, const float* __restrict__ whh2,
    const float* __restrict__ bih2, const float* __restrict__ bhh2,
    const float* __restrict__ wo1, const float* __restrict__ bo1,
    const float* __restrict__ wo2, const float* __restrict__ bo2,
    float* __restrict__ out, u16* __restrict__ hbuf, int* __restrict__ ctl)
{
  __shared__ float red[2][3][3][64][4];   // 36 KB partial-sum exchange
  const int wg = blockIdx.x;
  const int tid = threadIdx.x;
  const int lane = tid & 63;
  const int w = tid >> 6;
  const int l15 = lane & 15;
  const int q = lane >> 4;

  int* flagL1  = ctl;
  int* flagL2  = ctl + 64;
  int* flagOUT = ctl + 128;
  u16* h1b = hbuf;                     // 4 * kBH
  u16* h2b = hbuf + 4 * kBH;           // 4 * kBH

  if (wg < 64) {
    // ---------------- layer 1 ----------------
    const int u0 = (wg & 31) * 16, g = wg >> 5, b0 = g * 32;
    const int ntl = w & 1, kh = w >> 1;        // kh = K-quarter (0..3)
    const int bb = b0 + ntl * 16 + l15;
    bf16x8 ahh[3][4];                           // 48 VGPRs w_hh1 frags
#pragma unroll
    for (int gg = 0; gg < 3; ++gg)
#pragma unroll
      for (int c = 0; c < 4; ++c)
        ahh[gg][c] = cvt8(whh1 + (gg * kH + u0 + l15) * kH + (kh * 4 + c) * 32 + q * 8);
    bf16x8 aih[3][2];
    float br[4], bz[4], bni[4], bnh[4], h1l[4];
    int bound = 0;
    // throttle watch set (kh==0 wave): lanes 0..31 flagL2 of group, 32..33 flagOUT
    const int thridx = (lane < 32) ? (64 + g * 32 + lane) : (128 + g * 2 + (lane & 1));
    const bool thract = (lane < 34);
    if (kh == 0) {
#pragma unroll
      for (int gg = 0; gg < 3; ++gg)
#pragma unroll
        for (int c = 0; c < 2; ++c)
          aih[gg][c] = cvt8(wih1 + (gg * kH + u0 + l15) * kI + c * 32 + q * 8);
#pragma unroll
      for (int r = 0; r < 4; ++r) {
        int u = u0 + q * 4 + r;
        br[r]  = bih1[u]          + bhh1[u];
        bz[r]  = bih1[kH + u]     + bhh1[kH + u];
        bni[r] = bih1[2 * kH + u];
        bnh[r] = bhh1[2 * kH + u];
        h1l[r] = 0.0f;                  // fp32 master h1 lives in regs
      }
    }
    const int fbase = g * 32 + kh * 8;  // producers of this wave's K-quarter
    for (int k = 1; k <= kT; ++k) {
      const int t3 = k % 3, t3p = (k - 1) % 3;
      bf16x8 xf0, xf1;
      if (kh == 0) {                    // x prefetch (plain cached loads)
        const float* xs = x + (bb * kT + (k - 1)) * kI + q * 8;
        xf0 = cvt8(xs); xf1 = cvt8(xs + 32);
      }
      waitflag(flagL1, fbase + (lane & 7), k - 1);
      bf16x8 ch[4];
      dataN<4>(h1b + ((k - 1) & 3) * kBH + bb * kH + kh * 128 + q * 8, pat3(t3p), ch);
      f32x4 a0 = {0,0,0,0}, a1 = {0,0,0,0}, a2 = {0,0,0,0};
#pragma unroll
      for (int c = 0; c < 4; ++c) {
        a0 = mfma(ahh[0][c], ch[c], a0);
        a1 = mfma(ahh[1][c], ch[c], a1);
        a2 = mfma(ahh[2][c], ch[c], a2);
      }
      f32x4 x0 = {0,0,0,0}, x1 = {0,0,0,0}, x2 = {0,0,0,0};
      if (kh != 0) {
#pragma unroll
        for (int r = 0; r < 4; ++r) {
          red[ntl][kh - 1][0][lane][r] = a0[r];
          red[ntl][kh - 1][1][lane][r] = a1[r];
          red[ntl][kh - 1][2][lane][r] = a2[r];
        }
      } else {
        x0 = mfma(aih[0][0], xf0, x0); x0 = mfma(aih[0][1], xf1, x0);
        x1 = mfma(aih[1][0], xf0, x1); x1 = mfma(aih[1][1], xf1, x1);
        x2 = mfma(aih[2][0], xf0, x2); x2 = mfma(aih[2][1], xf1, x2);
        throttle(ctl, thridx, thract, k, bound);   // h1 anti-dep
      }
      __syncthreads();
      if (kh == 0) {
        float hnew[4];
#pragma unroll
        for (int r = 0; r < 4; ++r) {
          float gh0 = a0[r] + red[ntl][0][0][lane][r] + red[ntl][1][0][lane][r] + red[ntl][2][0][lane][r];
          float gh1 = a1[r] + red[ntl][0][1][lane][r] + red[ntl][1][1][lane][r] + red[ntl][2][1][lane][r];
          float gh2 = a2[r] + red[ntl][0][2][lane][r] + red[ntl][1][2][lane][r] + red[ntl][2][2][lane][r];
          float rr = sigf(x0[r] + gh0 + br[r]);
          float zz = sigf(x1[r] + gh1 + bz[r]);
          float nn = tanhf_(x2[r] + bni[r] + rr * (gh2 + bnh[r]));
          float h  = (1.0f - zz) * nn + zz * h1l[r];
          h1l[r] = h; hnew[r] = h;
        }
        st_h(h1b + (k & 3) * kBH + bb * kH + u0 + q * 4, hnew, t3);
      }
      __syncthreads();                  // drains h stores; guards red
      if (tid == 0) stflag(flagL1, wg, k);
    }
  } else if (wg < 128) {
    // ---------------- layer 2 ----------------
    const int g2 = wg - 64;
    const int u0 = (g2 & 31) * 16, g = g2 >> 5, b0 = g * 32;
    const int ntl = w & 1, mat = (w >> 1) & 1, kh = w >> 2;  // kh = K-half
    const int bb = b0 + ntl * 16 + l15;
    const float* wsrc = mat ? whh2 : wih2;
    bf16x8 af[3][8];                            // 96 VGPRs resident weights
#pragma unroll
    for (int gg = 0; gg < 3; ++gg)
#pragma unroll
      for (int c = 0; c < 8; ++c)
        af[gg][c] = cvt8(wsrc + (gg * kH + u0 + l15) * kH + (kh * 8 + c) * 32 + q * 8);
    const bool upd = (mat == 0 && kh == 0);
    float br[4], bz[4], bni[4], bnh[4], h2l[4];
    int bound = 0;
    const int thridx = 128 + g * 2 + (lane & 1);   // flagOUT pair
    const bool thract = (lane < 2);
    if (upd) {
#pragma unroll
      for (int r = 0; r < 4; ++r) {
        int u = u0 + q * 4 + r;
        br[r]  = bih2[u]          + bhh2[u];
        bz[r]  = bih2[kH + u]     + bhh2[kH + u];
        bni[r] = bih2[2 * kH + u];
        bnh[r] = bhh2[2 * kH + u];
        h2l[r] = 0.0f;
      }
    }
    const int fb1 = g * 32 + kh * 16;        // flagL1 producers of K-half
    const int fb2 = 64 + g * 32 + kh * 16;   // flagL2 producers of K-half
    for (int k = 1; k <= kT; ++k) {
      const int t3 = k % 3, t3p = (k - 1) % 3;
      if (mat == 0) waitflag(ctl, fb1 + (lane & 15), k);
      else          waitflag(ctl, fb2 + (lane & 15), k - 1);
      const u16* base = (mat == 0) ? h1b + (k & 3) * kBH : h2b + ((k - 1) & 3) * kBH;
      bf16x8 ch[8];
      dataN<8>(base + bb * kH + kh * 256 + q * 8, pat3(mat == 0 ? t3 : t3p), ch);
      f32x4 a0 = {0,0,0,0}, a1 = {0,0,0,0}, a2 = {0,0,0,0};
#pragma unroll
      for (int c = 0; c < 8; ++c) {
        a0 = mfma(af[0][c], ch[c], a0);
        a1 = mfma(af[1][c], ch[c], a1);
        a2 = mfma(af[2][c], ch[c], a2);
      }
      if (!upd) {
        const int s = mat * 2 + kh - 1;   // (0,1)->0 (1,0)->1 (1,1)->2
#pragma unroll
        for (int r = 0; r < 4; ++r) {
          red[ntl][s][0][lane][r] = a0[r];
          red[ntl][s][1][lane][r] = a1[r];
          red[ntl][s][2][lane][r] = a2[r];
        }
      } else {
        throttle(ctl, thridx, thract, k, bound);   // h2 anti-dep (OUT)
      }
      __syncthreads();
      if (upd) {
        float hnew[4];
#pragma unroll
        for (int r = 0; r < 4; ++r) {
          float gi0 = a0[r] + red[ntl][0][0][lane][r];
          float gi1 = a1[r] + red[ntl][0][1][lane][r];
          float gi2 = a2[r] + red[ntl][0][2][lane][r];
          float gh0 = red[ntl][1][0][lane][r] + red[ntl][2][0][lane][r];
          float gh1 = red[ntl][1][1][lane][r] + red[ntl][2][1][lane][r];
          float gh2 = red[ntl][1][2][lane][r] + red[ntl][2][2][lane][r];
          float rr = sigf(gi0 + gh0 + br[r]);
          float zz = sigf(gi1 + gh1 + bz[r]);
          float nn = tanhf_(gi2 + bni[r] + rr * (gh2 + bnh[r]));
          float h  = (1.0f - zz) * nn + zz * h2l[r];
          h2l[r] = h; hnew[r] = h;
        }
        st_h(h2b + (k & 3) * kBH + bb * kH + u0 + q * 4, hnew, t3);
      }
      __syncthreads();                  // drains h2 stores; guards red
      if (tid == 0) stflag(flagL2, g2, k);   // also certifies h1[k] consumed
    }
  } else {
    // ---------------- output head ----------------
    const int g3 = wg - 128, G = g3 >> 1;
    const int bb = g3 * 16 + l15;
    const int mat = w & 1, khh = (w >> 1) & 1, rt = w >> 2;
    const float* wsel = mat ? wo2 : wo1;
    const int row = rt * 16 + l15;
    bf16x8 zf = {0,0,0,0,0,0,0,0};
    bf16x8 af[8];
#pragma unroll
    for (int c = 0; c < 8; ++c)
      af[c] = (row < kO) ? cvt8(wsel + row * kH + (khh * 8 + c) * 32 + q * 8) : zf;
    const bool fin = (mat == 0 && khh == 0);
    float bv1[4], bv2[4];
    if (fin) {
#pragma unroll
      for (int r = 0; r < 4; ++r) {
        int o = rt * 16 + q * 4 + r;
        bv1[r] = (o < kO) ? bo1[o] : 0.0f;
        bv2[r] = (o < kO) ? bo2[o] : 0.0f;
      }
    }
    const u16* hb = (mat == 0) ? h1b : h2b;
    const int fb = (mat == 0 ? 0 : 64) + G * 32 + khh * 16;
    for (int k = 1; k <= kT; ++k) {
      const u32 pat = pat3(k % 3);
      waitflag(ctl, fb + (lane & 15), k);
      bf16x8 ch[8];
      dataN<8>(hb + (k & 3) * kBH + bb * kH + khh * 256 + q * 8, pat, ch);
      f32x4 a0 = {0,0,0,0};
#pragma unroll
      for (int c = 0; c < 8; ++c) a0 = mfma(af[c], ch[c], a0);
      if (!fin) {
        const int s = mat * 2 + khh - 1;
#pragma unroll
        for (int r = 0; r < 4; ++r) red[rt][s][0][lane][r] = a0[r];
      }
      __syncthreads();
      if (fin) {
        int o0 = rt * 16 + q * 4;
        if (o0 < kO) {
          float4 ov;
          ov.x = tanhf_(a0[0] + red[rt][0][0][lane][0] + bv1[0]) +
                 tanhf_(red[rt][1][0][lane][0] + red[rt][2][0][lane][0] + bv2[0]);
          ov.y = tanhf_(a0[1] + red[rt][0][0][lane][1] + bv1[1]) +
                 tanhf_(red[rt][1][0][lane][1] + red[rt][2][0][lane][1] + bv2[1]);
          ov.z = tanhf_(a0[2] + red[rt][0][0][lane][2] + bv1[2]) +
                 tanhf_(red[rt][1][0][lane][2] + red[rt][2][0][lane][2] + bv2[2]);
          ov.w = tanhf_(a0[3] + red[rt][0][0][lane][3] + bv1[3]) +
                 tanhf_(red[rt][1][0][lane][3] + red[rt][2][0][lane][3] + bv2[3]);
          *reinterpret_cast<float4*>(out + (bb * kT + (k - 1)) * kO + o0) = ov;
        }
      }
      if (tid == 0) stflag(flagOUT, g3, k);
      __syncthreads();                  // guards red
    }
  }
}

extern "C" void kernel_launch(void* const* d_in, const int* in_sizes, int n_in,
                              void* d_out, int out_size, void* d_ws, size_t ws_size,
                              hipStream_t stream) {
  (void)in_sizes; (void)n_in; (void)out_size; (void)ws_size;
  // zero h buffers + control page; invalid-tag init for buf 3 of h1 & h2
  hipMemsetAsync(d_ws, 0, kBarOff + 1024, stream);
  hipMemsetAsync((char*)d_ws + 3u * kBH * 2u, 0x01, kBH * 2u, stream);  // h1 buf3
  hipMemsetAsync((char*)d_ws + 7u * kBH * 2u, 0x01, kBH * 2u, stream);  // h2 buf3
  const float* x    = (const float*)d_in[0];
  const float* wih1 = (const float*)d_in[1];
  const float* whh1 = (const float*)d_in[2];
  const float* bih1 = (const float*)d_in[3];
  const float* bhh1 = (const float*)d_in[4];
  const float* wih2 = (const float*)d_in[5];
  const float* whh2 = (const float*)d_in[6];
  const float* bih2 = (const float*)d_in[7];
  const float* bhh2 = (const float*)d_in[8];
  const float* wo1  = (const float*)d_in[9];
  const float* bo1  = (const float*)d_in[10];
  const float* wo2  = (const float*)d_in[11];
  const float* bo2  = (const float*)d_in[12];
  float* out  = (float*)d_out;
  u16* hbuf   = (u16*)d_ws;
  int* ctl    = (int*)((char*)d_ws + kBarOff);
  stackgru<<<dim3(kNWG), dim3(512), 0, stream>>>(
      x, wih1, whh1, bih1, bhh1, wih2, whh2, bih2, bhh2,
      wo1, bo1, wo2, bo2, out, hbuf, ctl);
}